// Round 17
// baseline (135.751 us; speedup 1.0000x reference)
//
#include <hip/hip_runtime.h>
#include <hip/hip_bf16.h>

#define BT      8192
#define DIN     2048
#define DOUT    2048
#define NEXP    8
#define RANK    8
#define KX      2112         /* DIN + NEXP*RANK */
#define NSUB    66           /* KX / 32 */
#define NSPLIT  4            /* K-split for the h-GEMM */
#define HLD     72           /* HP leading dim: cols 0-7 logits, 8-71 h */
#define SCALING 1.0f         /* ALPHA / RANK = 8/8 */
#define SLOTA   16384        /* A 256 rows x 64 B */

typedef __bf16 bf16x8 __attribute__((ext_vector_type(8)));
typedef __bf16 bf16x4 __attribute__((ext_vector_type(4)));
typedef float  f32x4  __attribute__((ext_vector_type(4)));

/* ---- ws layout (bytes) ---- */
#define XB_OFF     0
#define XB_BYTES   (BT * KX * 2)
#define WB_OFF     (XB_OFF + XB_BYTES)
#define WB_BYTES   (DOUT * KX * 2)
#define ACAT_OFF   (WB_OFF + WB_BYTES)
#define ACAT_BYTES (128 * DIN * 2)
#define HP_OFF     (ACAT_OFF + ACAT_BYTES)
#define HP_BYTES   (NSPLIT * BT * HLD * 4)

__device__ __forceinline__ void gload_lds16(const void* g, void* l) {
    __builtin_amdgcn_global_load_lds(
        (__attribute__((address_space(1))) void*)(g),
        (__attribute__((address_space(3))) void*)(l),
        16, 0, 0);
}

#define MFMA16(a, b, c) __builtin_amdgcn_mfma_f32_16x16x32_bf16((a), (b), (c), 0, 0, 0)

/* ---------------- prep: weights -> bf16 staged layouts ---------------- */
__global__ __launch_bounds__(256) void mole_prep(
    const float* __restrict__ Wf, const float* __restrict__ Bm,
    const float* __restrict__ Wr, const float* __restrict__ A,
    __bf16* __restrict__ WB, __bf16* __restrict__ ACAT)
{
    const int i = blockIdx.x * 256 + threadIdx.x;
    const int R1 = DOUT * (DIN / 4);
    const int R2 = DOUT * 64;
    if (i < R1) {
        const int o = i >> 9, c4 = i & 511;
        float4 v = ((const float4*)Wf)[(size_t)o * 512 + c4];
        bf16x4 b; b[0] = (__bf16)v.x; b[1] = (__bf16)v.y; b[2] = (__bf16)v.z; b[3] = (__bf16)v.w;
        *(bf16x4*)&WB[(size_t)o * KX + (c4 << 2)] = b;
    } else if (i < R1 + R2) {
        const int j = i - R1;
        const int o = j >> 6, c = j & 63;
        const int e = c >> 3, r = c & 7;
        WB[(size_t)o * KX + DIN + c] = (__bf16)Bm[((size_t)e * DOUT + o) * RANK + r];
    } else {
        const int j = i - (R1 + R2);
        const int r = j >> 9, c4 = j & 511;
        float4 v;
        if (r < 8)        v = ((const float4*)Wr)[(size_t)r * 512 + c4];
        else if (r < 72)  v = ((const float4*)A)[(size_t)(r - 8) * 512 + c4];
        else              v = make_float4(0.f, 0.f, 0.f, 0.f);
        bf16x4 b; b[0] = (__bf16)v.x; b[1] = (__bf16)v.y; b[2] = (__bf16)v.z; b[3] = (__bf16)v.w;
        *(bf16x4*)&ACAT[(size_t)r * DIN + (c4 << 2)] = b;
    }
}

/* ==== fused h-GEMM: x(fp32)->bf16 convert + XB side-write + MFMA vs ACAT ==== */
__global__ __launch_bounds__(256) void mole_hconv(
    const float* __restrict__ x, const __bf16* __restrict__ ACAT,
    __bf16* __restrict__ XB, float* __restrict__ HP)
{
    __shared__ __align__(16) __bf16 Xs[128][32];
    __shared__ __align__(16) __bf16 Bs[128][32];

    const int tid = threadIdx.x;
    const int wv  = tid >> 6, ln = tid & 63;
    const int wr  = wv >> 1, wc = wv & 1;
    const size_t m0 = (size_t)blockIdx.x * 128;
    const int kStart = blockIdx.z * (DIN / NSPLIT);
    float* C = HP + (size_t)blockIdx.z * BT * HLD;

    const int xr = tid >> 3;
    const int xc = (tid & 7) << 2;
    const float* gx  = x  + (m0 + xr) * (size_t)DIN + kStart + xc;
    __bf16*      gxb = XB + (m0 + xr) * (size_t)KX  + kStart + xc;

    const int srow = (wv << 4) + (ln >> 2);
    const int scol = (ln & 3) << 3;
    const __bf16* gB0 = ACAT + srow * (size_t)DIN + kStart + scol;
    const __bf16* gB1 = gB0 + (size_t)64 * DIN;
    __bf16* lB0 = &Bs[(wv << 4)][0];
    __bf16* lB1 = &Bs[64 + (wv << 4)][0];

    f32x4 acc[4][4] = {};
    const int fr = ln & 15;
    const int fk = (ln >> 4) << 3;

    for (int ks = 0; ks < (DIN / NSPLIT) / 32; ++ks) {
        gload_lds16(gB0, lB0);
        gload_lds16(gB1, lB1);
        gB0 += 32; gB1 += 32;
        #pragma unroll
        for (int j = 0; j < 4; ++j) {
            float4 v = *(const float4*)(gx + (size_t)(32 * j) * DIN + 32 * ks);
            bf16x4 b; b[0] = (__bf16)v.x; b[1] = (__bf16)v.y;
            b[2] = (__bf16)v.z; b[3] = (__bf16)v.w;
            *(bf16x4*)&Xs[xr + 32 * j][xc] = b;
            *(bf16x4*)(gxb + (size_t)(32 * j) * KX + 32 * ks) = b;
        }
        __syncthreads();

        bf16x8 af[4], bfr[4];
        #pragma unroll
        for (int m = 0; m < 4; ++m)
            af[m] = *(const bf16x8*)&Xs[(wr << 6) + (m << 4) + fr][fk];
        #pragma unroll
        for (int n = 0; n < 4; ++n)
            bfr[n] = *(const bf16x8*)&Bs[(wc << 6) + (n << 4) + fr][fk];
        #pragma unroll
        for (int m = 0; m < 4; ++m)
            #pragma unroll
            for (int n = 0; n < 4; ++n)
                acc[m][n] = MFMA16(af[m], bfr[n], acc[m][n]);
        __syncthreads();
    }

    const int cr = (ln >> 4) << 2;
    const int cc = ln & 15;
    #pragma unroll
    for (int n = 0; n < 4; ++n) {
        const int col = (wc << 6) + (n << 4) + cc;
        if (col < HLD) {
            #pragma unroll
            for (int m = 0; m < 4; ++m) {
                const size_t row = m0 + (wr << 6) + (m << 4) + cr;
                #pragma unroll
                for (int r = 0; r < 4; ++r)
                    C[(row + r) * (size_t)HLD + col] = acc[m][n][r];
            }
        }
    }
}

/* --------- per-token: logits (HP cols 0-7 + br) -> softmax -> w; g -> XB --- */
__global__ __launch_bounds__(256) void mole_softmax_g(
    const float* __restrict__ HP, const float* __restrict__ br,
    float* __restrict__ wOut, __bf16* __restrict__ XB)
{
    const int t   = blockIdx.x * 4 + (threadIdx.x >> 6);
    const int tid = threadIdx.x & 63;
    float h = 0.0f;
    #pragma unroll
    for (int sp = 0; sp < NSPLIT; ++sp)
        h += HP[((size_t)sp * BT + t) * HLD + 8 + tid];

    float lg[NEXP];
    #pragma unroll
    for (int e = 0; e < NEXP; ++e) {
        lg[e] = br[e];
        #pragma unroll
        for (int sp = 0; sp < NSPLIT; ++sp)
            lg[e] += HP[((size_t)sp * BT + t) * HLD + e];
    }
    float mx = lg[0];
    #pragma unroll
    for (int e = 1; e < NEXP; ++e) mx = fmaxf(mx, lg[e]);
    float ex[NEXP], den = 0.0f;
    #pragma unroll
    for (int e = 0; e < NEXP; ++e) { ex[e] = expf(lg[e] - mx); den += ex[e]; }

    const float w_my = ex[tid >> 3] / den;
    XB[(size_t)t * KX + DIN + tid] = (__bf16)(SCALING * w_my * h);
    if (tid < NEXP) wOut[(size_t)t * NEXP + tid] = ex[tid] / den;
}

/* ==== main 256x256 GEMM: A via LDS ring-4, B DIRECT global->VGPR ====
   C[8192,2048] = XB * WB^T + bias. AITER pattern: one operand bypasses
   LDS entirely. B-frag for mfma_16x16x32 is per-lane 16B contiguous
   (row n0+wn*64+nf*16+(l&15), k-offset (l>>4)*8) -> global_load_dwordx4
   straight to registers via L2 (idle path; ~9 TB/s needed vs 34.5).
   LDS cost/step drops: reads 12->8 b128/wave, DMA writes 32->16 KB.
   LDS = 4 ring slots x 16 KB (A 256x64B rows; swizzle phys16B =
   k ^ ((row>>1)&3), 0-conflict verified; pre-swizzled global source).
   Per step/thread issue: 4 B-loads(s+1) + 2 A-stages(s+3).
   FIFO ledger: entry of step s outstanding = [A(s+1)x2, B(s)x4, A(s+2)x2]
   -> vmcnt(2) drains exactly B(s) (+A(s+1), early but harmless).
   B-frags double-buffered in NAMED regs (fbg0/fbg1, rule 20).
   Tail: vmcnt 2/2/0/0; never 0 until the last two steps. */
__global__ __launch_bounds__(512, 1) void mole_gemm256(
    const __bf16* __restrict__ XBp, const __bf16* __restrict__ WBp,
    float* __restrict__ C, const float* __restrict__ bias)
{
    __shared__ __align__(16) char smem[65536];

    const int tid = threadIdx.x;
    const int wv  = tid >> 6, l = tid & 63;
    const int wm  = wv >> 2, wn = wv & 3;
    const int bid = blockIdx.x;
    const int xcd = bid & 7, ib = bid >> 3;
    const int tm = xcd * 4 + (ib & 3), tn = ib >> 2;
    const size_t m0 = (size_t)tm * 256, n0 = (size_t)tn * 256;

    /* A staging: wave wv stages rows [32wv, 32wv+32), 2 instr x 16 rows.
       lane l -> row +(l>>2), phys slot l&3, logical col ((l&3)^((l>>3)&3))*8 */
    const int swcol = ((l & 3) ^ ((l >> 3) & 3)) << 3;
    const __bf16* gsA = XBp + (m0 + 32 * wv + (l >> 2)) * (size_t)KX + swcol;
    const int dA = wv * 2048;

    /* B direct-to-register fragment pointer */
    const __bf16* gBf = WBp + (n0 + wn * 64 + (l & 15)) * (size_t)KX + ((l >> 4) << 3);

    /* A fragment read: row R, logical k-slot fq -> phys fq ^ ((R>>1)&3) */
    const int fr = l & 15, fq = l >> 4;
    const int swz = (fq ^ ((fr >> 1) & 3)) << 4;
    const int aByte = (wm * 128 + fr) * 64 + swz;

    f32x4 acc[8][4] = {};
    bf16x8 fbg0[4], fbg1[4];

#define STAGEA(S)                                                             \
    {                                                                         \
        char* dst = smem + ((S) & 3) * SLOTA + dA;                            \
        const __bf16* g = gsA + (size_t)(S) * 32;                             \
        gload_lds16(g, dst);                                                  \
        gload_lds16(g + (size_t)16 * KX, dst + 1024);                         \
    }

#define LOADB(S, FB)                                                          \
    {                                                                         \
        _Pragma("unroll")                                                     \
        for (int nf = 0; nf < 4; ++nf)                                        \
            FB[nf] = *(const bf16x8*)(gBf + (size_t)nf * 16 * KX              \
                                          + (size_t)(S) * 32);                \
    }

#define STEP(S, VMN, DOSTAGE, DOLOADB, FBc, FBn)                              \
    {                                                                         \
        asm volatile("s_waitcnt vmcnt(" #VMN ")" ::: "memory");               \
        __builtin_amdgcn_s_barrier();                                         \
        const char* slot = smem + ((S) & 3) * SLOTA;                          \
        bf16x8 fa[8];                                                         \
        _Pragma("unroll")                                                     \
        for (int mf = 0; mf < 8; ++mf)                                        \
            fa[mf] = *(const bf16x8*)(slot + aByte + mf * 1024);              \
        if (DOLOADB) LOADB((S) + 1, FBn);                                     \
        if (DOSTAGE) STAGEA((S) + 3);                                         \
        __builtin_amdgcn_sched_barrier(0);                                    \
        __builtin_amdgcn_s_setprio(1);                                        \
        _Pragma("unroll")                                                     \
        for (int mf = 0; mf < 8; ++mf)                                        \
            _Pragma("unroll")                                                 \
            for (int nf = 0; nf < 4; ++nf)                                    \
                acc[mf][nf] = MFMA16(fa[mf], FBc[nf], acc[mf][nf]);           \
        __builtin_amdgcn_s_setprio(0);                                        \
    }

    /* prologue: stage A chunks 0,1,2; load B(0); full drain; publish */
    STAGEA(0); STAGEA(1); STAGEA(2);
    LOADB(0, fbg0);
    asm volatile("s_waitcnt vmcnt(0)" ::: "memory");
    __builtin_amdgcn_s_barrier();

    #pragma unroll 1
    for (int s = 0; s < 62; s += 2) {
        STEP(s,     2, true, true, fbg0, fbg1);
        STEP(s + 1, 2, true, true, fbg1, fbg0);
    }
    STEP(62, 2, true,  true,  fbg0, fbg1);   /* stages chunk 65, loads B63 */
    STEP(63, 2, false, true,  fbg1, fbg0);   /* loads B64 */
    STEP(64, 0, false, true,  fbg0, fbg1);   /* loads B65 */
    STEP(65, 0, false, false, fbg1, fbg0);
#undef STEP
#undef LOADB
#undef STAGEA

    /* epilogue: C = acc + bias */
    const size_t crow = m0 + wm * 128 + fq * 4;
    const size_t ccol = n0 + wn * 64 + fr;
    #pragma unroll
    for (int nf = 0; nf < 4; ++nf) {
        const float bv = bias[ccol + nf * 16];
        #pragma unroll
        for (int mf = 0; mf < 8; ++mf) {
            float* cp = C + (crow + (size_t)mf * 16) * DOUT + ccol + nf * 16;
            #pragma unroll
            for (int i = 0; i < 4; ++i)
                cp[(size_t)i * DOUT] = acc[mf][nf][i] + bv;
        }
    }
}

extern "C" void kernel_launch(void* const* d_in, const int* in_sizes, int n_in,
                              void* d_out, int out_size, void* d_ws, size_t ws_size,
                              hipStream_t stream) {
    const float* x  = (const float*)d_in[0];
    const float* Wf = (const float*)d_in[1];
    const float* bf = (const float*)d_in[2];
    const float* Wr = (const float*)d_in[3];
    const float* br = (const float*)d_in[4];
    const float* A  = (const float*)d_in[5];
    const float* Bm = (const float*)d_in[6];

    float* out0 = (float*)d_out;
    float* wOut = out0 + (size_t)BT * DOUT;

    char* ws = (char*)d_ws;
    __bf16* XB   = (__bf16*)(ws + XB_OFF);
    __bf16* WB   = (__bf16*)(ws + WB_OFF);
    __bf16* ACAT = (__bf16*)(ws + ACAT_OFF);
    float*  HP   = (float*)(ws + HP_OFF);

    /* 1. weights -> bf16 layouts */
    mole_prep<<<4864, 256, 0, stream>>>(Wf, Bm, Wr, A, WB, ACAT);
    /* 2. fused: x->bf16 (+XB side-write) + [logit|h] partials vs ACAT */
    mole_hconv<<<dim3(64, 1, NSPLIT), 256, 0, stream>>>(x, ACAT, XB, HP);
    /* 3. softmax(+br) -> w out; g -> XB tail cols */
    mole_softmax_g<<<BT / 4, 256, 0, stream>>>(HP, br, wOut, XB);
    /* 4. out = [xb|g] @ [Wfb|Bcat]^T + bf  (A via LDS, B direct-to-reg) */
    mole_gemm256<<<256, 512, 0, stream>>>(XB, WB, out0, bf);
}

// Round 18
// 102.979 us; speedup vs baseline: 1.3182x; 1.3182x over previous
//
#include <hip/hip_runtime.h>
#include <hip/hip_bf16.h>

#define BT      8192
#define DIN     2048
#define DOUT    2048
#define NEXP    8
#define RANK    8
#define KX      2112         /* DIN + NEXP*RANK */
#define NSUB    66           /* KX / 32 */
#define NSPLIT  4            /* K-split for the h-GEMM */
#define HLD     72           /* HP leading dim: cols 0-7 logits, 8-71 h */
#define SCALING 1.0f         /* ALPHA / RANK = 8/8 */
#define SLOT    32768
#define LDSZ    163840       /* 5 ring slots x 32 KB = full 160 KB CU LDS */

typedef __bf16 bf16x8 __attribute__((ext_vector_type(8)));
typedef __bf16 bf16x4 __attribute__((ext_vector_type(4)));
typedef float  f32x4  __attribute__((ext_vector_type(4)));

/* ---- ws layout (bytes) ---- */
#define XB_OFF     0
#define XB_BYTES   (BT * KX * 2)
#define WB_OFF     (XB_OFF + XB_BYTES)
#define WB_BYTES   (DOUT * KX * 2)
#define ACAT_OFF   (WB_OFF + WB_BYTES)
#define ACAT_BYTES (128 * DIN * 2)
#define HP_OFF     (ACAT_OFF + ACAT_BYTES)
#define HP_BYTES   (NSPLIT * BT * HLD * 4)

__device__ __forceinline__ void gload_lds16(const void* g, void* l) {
    __builtin_amdgcn_global_load_lds(
        (__attribute__((address_space(1))) void*)(g),
        (__attribute__((address_space(3))) void*)(l),
        16, 0, 0);
}

#define MFMA16(a, b, c) __builtin_amdgcn_mfma_f32_16x16x32_bf16((a), (b), (c), 0, 0, 0)

/* ---------------- prep: weights -> bf16 staged layouts ---------------- */
__global__ __launch_bounds__(256) void mole_prep(
    const float* __restrict__ Wf, const float* __restrict__ Bm,
    const float* __restrict__ Wr, const float* __restrict__ A,
    __bf16* __restrict__ WB, __bf16* __restrict__ ACAT)
{
    const int i = blockIdx.x * 256 + threadIdx.x;
    const int R1 = DOUT * (DIN / 4);
    const int R2 = DOUT * 64;
    if (i < R1) {
        const int o = i >> 9, c4 = i & 511;
        float4 v = ((const float4*)Wf)[(size_t)o * 512 + c4];
        bf16x4 b; b[0] = (__bf16)v.x; b[1] = (__bf16)v.y; b[2] = (__bf16)v.z; b[3] = (__bf16)v.w;
        *(bf16x4*)&WB[(size_t)o * KX + (c4 << 2)] = b;
    } else if (i < R1 + R2) {
        const int j = i - R1;
        const int o = j >> 6, c = j & 63;
        const int e = c >> 3, r = c & 7;
        WB[(size_t)o * KX + DIN + c] = (__bf16)Bm[((size_t)e * DOUT + o) * RANK + r];
    } else {
        const int j = i - (R1 + R2);
        const int r = j >> 9, c4 = j & 511;
        float4 v;
        if (r < 8)        v = ((const float4*)Wr)[(size_t)r * 512 + c4];
        else if (r < 72)  v = ((const float4*)A)[(size_t)(r - 8) * 512 + c4];
        else              v = make_float4(0.f, 0.f, 0.f, 0.f);
        bf16x4 b; b[0] = (__bf16)v.x; b[1] = (__bf16)v.y; b[2] = (__bf16)v.z; b[3] = (__bf16)v.w;
        *(bf16x4*)&ACAT[(size_t)r * DIN + (c4 << 2)] = b;
    }
}

/* ==== fused h-GEMM: x(fp32)->bf16 convert + XB side-write + MFMA vs ACAT ==== */
__global__ __launch_bounds__(256) void mole_hconv(
    const float* __restrict__ x, const __bf16* __restrict__ ACAT,
    __bf16* __restrict__ XB, float* __restrict__ HP)
{
    __shared__ __align__(16) __bf16 Xs[128][32];
    __shared__ __align__(16) __bf16 Bs[128][32];

    const int tid = threadIdx.x;
    const int wv  = tid >> 6, ln = tid & 63;
    const int wr  = wv >> 1, wc = wv & 1;
    const size_t m0 = (size_t)blockIdx.x * 128;
    const int kStart = blockIdx.z * (DIN / NSPLIT);
    float* C = HP + (size_t)blockIdx.z * BT * HLD;

    const int xr = tid >> 3;
    const int xc = (tid & 7) << 2;
    const float* gx  = x  + (m0 + xr) * (size_t)DIN + kStart + xc;
    __bf16*      gxb = XB + (m0 + xr) * (size_t)KX  + kStart + xc;

    const int srow = (wv << 4) + (ln >> 2);
    const int scol = (ln & 3) << 3;
    const __bf16* gB0 = ACAT + srow * (size_t)DIN + kStart + scol;
    const __bf16* gB1 = gB0 + (size_t)64 * DIN;
    __bf16* lB0 = &Bs[(wv << 4)][0];
    __bf16* lB1 = &Bs[64 + (wv << 4)][0];

    f32x4 acc[4][4] = {};
    const int fr = ln & 15;
    const int fk = (ln >> 4) << 3;

    for (int ks = 0; ks < (DIN / NSPLIT) / 32; ++ks) {
        gload_lds16(gB0, lB0);
        gload_lds16(gB1, lB1);
        gB0 += 32; gB1 += 32;
        #pragma unroll
        for (int j = 0; j < 4; ++j) {
            float4 v = *(const float4*)(gx + (size_t)(32 * j) * DIN + 32 * ks);
            bf16x4 b; b[0] = (__bf16)v.x; b[1] = (__bf16)v.y;
            b[2] = (__bf16)v.z; b[3] = (__bf16)v.w;
            *(bf16x4*)&Xs[xr + 32 * j][xc] = b;
            *(bf16x4*)(gxb + (size_t)(32 * j) * KX + 32 * ks) = b;
        }
        __syncthreads();

        bf16x8 af[4], bfr[4];
        #pragma unroll
        for (int m = 0; m < 4; ++m)
            af[m] = *(const bf16x8*)&Xs[(wr << 6) + (m << 4) + fr][fk];
        #pragma unroll
        for (int n = 0; n < 4; ++n)
            bfr[n] = *(const bf16x8*)&Bs[(wc << 6) + (n << 4) + fr][fk];
        #pragma unroll
        for (int m = 0; m < 4; ++m)
            #pragma unroll
            for (int n = 0; n < 4; ++n)
                acc[m][n] = MFMA16(af[m], bfr[n], acc[m][n]);
        __syncthreads();
    }

    const int cr = (ln >> 4) << 2;
    const int cc = ln & 15;
    #pragma unroll
    for (int n = 0; n < 4; ++n) {
        const int col = (wc << 6) + (n << 4) + cc;
        if (col < HLD) {
            #pragma unroll
            for (int m = 0; m < 4; ++m) {
                const size_t row = m0 + (wr << 6) + (m << 4) + cr;
                #pragma unroll
                for (int r = 0; r < 4; ++r)
                    C[(row + r) * (size_t)HLD + col] = acc[m][n][r];
            }
        }
    }
}

/* --------- per-token: logits (HP cols 0-7 + br) -> softmax -> w; g -> XB --- */
__global__ __launch_bounds__(256) void mole_softmax_g(
    const float* __restrict__ HP, const float* __restrict__ br,
    float* __restrict__ wOut, __bf16* __restrict__ XB)
{
    const int t   = blockIdx.x * 4 + (threadIdx.x >> 6);
    const int tid = threadIdx.x & 63;
    float h = 0.0f;
    #pragma unroll
    for (int sp = 0; sp < NSPLIT; ++sp)
        h += HP[((size_t)sp * BT + t) * HLD + 8 + tid];

    float lg[NEXP];
    #pragma unroll
    for (int e = 0; e < NEXP; ++e) {
        lg[e] = br[e];
        #pragma unroll
        for (int sp = 0; sp < NSPLIT; ++sp)
            lg[e] += HP[((size_t)sp * BT + t) * HLD + e];
    }
    float mx = lg[0];
    #pragma unroll
    for (int e = 1; e < NEXP; ++e) mx = fmaxf(mx, lg[e]);
    float ex[NEXP], den = 0.0f;
    #pragma unroll
    for (int e = 0; e < NEXP; ++e) { ex[e] = expf(lg[e] - mx); den += ex[e]; }

    const float w_my = ex[tid >> 3] / den;
    XB[(size_t)t * KX + DIN + tid] = (__bf16)(SCALING * w_my * h);
    if (tid < NEXP) wOut[(size_t)t * NEXP + tid] = ex[tid] / den;
}

/* ==== main 256x256 GEMM: ring-5 BK=32, PAIRED barriers (best measured:
   67.2-67.6 us, R8). 8 waves (2M x 4N), per-wave 128x64. LDS = 5 ring
   slots x 32 KB = 160 KB ([A 256x32 | B 256x32] bf16, 64 B/row; swizzle
   phys16B = k ^ ((row>>1)&3), 0-conflict verified; staged via pre-
   swizzled global source). Barrier every 2 steps; vmcnt(4) per pair
   completes exactly the 2 chunks the pair reads (flight-3 staging).
   WAR: pair writes slots s+3,s+4 (mod 5), reads s,s+1, prev readers
   fenced by the pair barrier -> distinct mod 5. Tail vmcnt 4/0. */
__global__ __launch_bounds__(512, 1) void mole_gemm256(
    const __bf16* __restrict__ XBp, const __bf16* __restrict__ WBp,
    float* __restrict__ C, const float* __restrict__ bias)
{
    __shared__ __align__(16) char smem[LDSZ];

    const int tid = threadIdx.x;
    const int wv  = tid >> 6, l = tid & 63;
    const int wm  = wv >> 2, wn = wv & 3;
    const int bid = blockIdx.x;
    const int xcd = bid & 7, ib = bid >> 3;
    const int tm = xcd * 4 + (ib & 3), tn = ib >> 2;
    const size_t m0 = (size_t)tm * 256, n0 = (size_t)tn * 256;

    const int op = wv >> 2, ww = wv & 3;
    const __bf16* gstage = (op == 0 ? XBp + (m0 + ww * 64) * KX
                                    : WBp + (n0 + ww * 64) * KX)
                         + (size_t)(l >> 2) * KX + (((l & 3) ^ ((l >> 3) & 3)) << 3);
    const int stageBase = op * 16384 + ww * 4096;

    const int fr = l & 15, fq = l >> 4;
    const int swz = (fq ^ ((fr >> 1) & 3)) << 4;
    const int aByte = (wm * 128 + fr) * 64 + swz;
    const int bByte = 16384 + (wn * 64 + fr) * 64 + swz;

    f32x4 acc[8][4] = {};

#define STAGEAT(STB, GS)                                                      \
    {                                                                         \
        char* dst = smem + (STB) + stageBase;                                 \
        _Pragma("unroll")                                                     \
        for (int j = 0; j < 4; ++j)                                           \
            gload_lds16((GS) + (size_t)j * 16 * KX, dst + j * 1024);          \
    }

#define STEPBODY(SB, GS, DOSTAGE, STB)                                        \
    {                                                                         \
        const char* slot = smem + (SB);                                       \
        bf16x8 fa[8], fb[4];                                                  \
        _Pragma("unroll")                                                     \
        for (int nf = 0; nf < 4; ++nf)                                        \
            fb[nf] = *(const bf16x8*)(slot + bByte + nf * 1024);              \
        _Pragma("unroll")                                                     \
        for (int mf = 0; mf < 8; ++mf)                                        \
            fa[mf] = *(const bf16x8*)(slot + aByte + mf * 1024);              \
        if (DOSTAGE) STAGEAT(STB, GS);                                        \
        __builtin_amdgcn_s_setprio(1);                                        \
        _Pragma("unroll")                                                     \
        for (int mf = 0; mf < 8; ++mf)                                        \
            _Pragma("unroll")                                                 \
            for (int nf = 0; nf < 4; ++nf)                                    \
                acc[mf][nf] = MFMA16(fa[mf], fb[nf], acc[mf][nf]);            \
        __builtin_amdgcn_s_setprio(0);                                        \
    }

    /* prologue: stage chunks 0,1,2 -> slots 0,1,2 (12 loads/thread) */
    STAGEAT(0 * SLOT, gstage + 0 * 32);
    STAGEAT(1 * SLOT, gstage + 1 * 32);
    STAGEAT(2 * SLOT, gstage + 2 * 32);

    int sb = 0;                           /* byte of slot s%5 (pair start) */
    const __bf16* gsn = gstage + 96;      /* source of chunk s+3           */

    #pragma unroll 1
    for (int s = 0; s < 62; s += 2) {
        asm volatile("s_waitcnt vmcnt(4)" ::: "memory");
        __builtin_amdgcn_s_barrier();
        int sb1 = sb + SLOT;     if (sb1 >= LDSZ) sb1 -= LDSZ;
        int st0 = sb + 3 * SLOT; if (st0 >= LDSZ) st0 -= LDSZ;
        int st1 = sb + 4 * SLOT; if (st1 >= LDSZ) st1 -= LDSZ;
        STEPBODY(sb,  gsn,      1, st0);
        STEPBODY(sb1, gsn + 32, 1, st1);
        gsn += 64;
        sb = sb1 + SLOT; if (sb >= LDSZ) sb -= LDSZ;
    }
    /* pair 62: stage chunk 65 only (step 62) */
    {
        asm volatile("s_waitcnt vmcnt(4)" ::: "memory");
        __builtin_amdgcn_s_barrier();
        int sb1 = sb + SLOT;     if (sb1 >= LDSZ) sb1 -= LDSZ;
        int st0 = sb + 3 * SLOT; if (st0 >= LDSZ) st0 -= LDSZ;
        STEPBODY(sb,  gsn, 1, st0);
        STEPBODY(sb1, gsn, 0, 0);
        sb = sb1 + SLOT; if (sb >= LDSZ) sb -= LDSZ;
    }
    /* pair 64: drain all */
    {
        asm volatile("s_waitcnt vmcnt(0)" ::: "memory");
        __builtin_amdgcn_s_barrier();
        int sb1 = sb + SLOT;     if (sb1 >= LDSZ) sb1 -= LDSZ;
        STEPBODY(sb,  gsn, 0, 0);
        STEPBODY(sb1, gsn, 0, 0);
    }
#undef STEPBODY
#undef STAGEAT

    /* epilogue: C = acc + bias */
    const size_t crow = m0 + wm * 128 + fq * 4;
    const size_t ccol = n0 + wn * 64 + fr;
    #pragma unroll
    for (int nf = 0; nf < 4; ++nf) {
        const float bv = bias[ccol + nf * 16];
        #pragma unroll
        for (int mf = 0; mf < 8; ++mf) {
            float* cp = C + (crow + (size_t)mf * 16) * DOUT + ccol + nf * 16;
            #pragma unroll
            for (int i = 0; i < 4; ++i)
                cp[(size_t)i * DOUT] = acc[mf][nf][i] + bv;
        }
    }
}

extern "C" void kernel_launch(void* const* d_in, const int* in_sizes, int n_in,
                              void* d_out, int out_size, void* d_ws, size_t ws_size,
                              hipStream_t stream) {
    const float* x  = (const float*)d_in[0];
    const float* Wf = (const float*)d_in[1];
    const float* bf = (const float*)d_in[2];
    const float* Wr = (const float*)d_in[3];
    const float* br = (const float*)d_in[4];
    const float* A  = (const float*)d_in[5];
    const float* Bm = (const float*)d_in[6];

    float* out0 = (float*)d_out;
    float* wOut = out0 + (size_t)BT * DOUT;

    char* ws = (char*)d_ws;
    __bf16* XB   = (__bf16*)(ws + XB_OFF);
    __bf16* WB   = (__bf16*)(ws + WB_OFF);
    __bf16* ACAT = (__bf16*)(ws + ACAT_OFF);
    float*  HP   = (float*)(ws + HP_OFF);

    /* 1. weights -> bf16 layouts */
    mole_prep<<<4864, 256, 0, stream>>>(Wf, Bm, Wr, A, WB, ACAT);
    /* 2. fused: x->bf16 (+XB side-write) + [logit|h] partials vs ACAT */
    mole_hconv<<<dim3(64, 1, NSPLIT), 256, 0, stream>>>(x, ACAT, XB, HP);
    /* 3. softmax(+br) -> w out; g -> XB tail cols */
    mole_softmax_g<<<BT / 4, 256, 0, stream>>>(HP, br, wOut, XB);
    /* 4. out = [xb|g] @ [Wfb|Bcat]^T + bf  (ring-5 paired, best measured) */
    mole_gemm256<<<256, 512, 0, stream>>>(XB, WB, out0, bf);
}

// Round 19
// 100.736 us; speedup vs baseline: 1.3476x; 1.0223x over previous
//
#include <hip/hip_runtime.h>
#include <hip/hip_bf16.h>

#define BT      8192
#define DIN     2048
#define DOUT    2048
#define NEXP    8
#define RANK    8
#define KX      2112         /* DIN + NEXP*RANK */
#define NSPLIT  4            /* K-split for the h-GEMM */
#define HLD     72           /* HP leading dim: cols 0-7 logits, 8-71 h */
#define SCALING 1.0f         /* ALPHA / RANK = 8/8 */

typedef __bf16 bf16x8 __attribute__((ext_vector_type(8)));
typedef __bf16 bf16x4 __attribute__((ext_vector_type(4)));
typedef float  f32x4  __attribute__((ext_vector_type(4)));

/* ---- ws layout (bytes) ---- */
#define XB_OFF     0
#define XB_BYTES   (BT * KX * 2)
#define WB_OFF     (XB_OFF + XB_BYTES)
#define WB_BYTES   (DOUT * KX * 2)
#define ACAT_OFF   (WB_OFF + WB_BYTES)
#define ACAT_BYTES (128 * DIN * 2)
#define HP_OFF     (ACAT_OFF + ACAT_BYTES)
#define HP_BYTES   (NSPLIT * BT * HLD * 4)

__device__ __forceinline__ void gload_lds16(const void* g, void* l) {
    __builtin_amdgcn_global_load_lds(
        (__attribute__((address_space(1))) void*)(g),
        (__attribute__((address_space(3))) void*)(l),
        16, 0, 0);
}

#define MFMA16(a, b, c) __builtin_amdgcn_mfma_f32_16x16x32_bf16((a), (b), (c), 0, 0, 0)

/* ---------------- prep: weights -> bf16 staged layouts ---------------- */
__global__ __launch_bounds__(256) void mole_prep(
    const float* __restrict__ Wf, const float* __restrict__ Bm,
    const float* __restrict__ Wr, const float* __restrict__ A,
    __bf16* __restrict__ WB, __bf16* __restrict__ ACAT)
{
    const int i = blockIdx.x * 256 + threadIdx.x;
    const int R1 = DOUT * (DIN / 4);
    const int R2 = DOUT * 64;
    if (i < R1) {
        const int o = i >> 9, c4 = i & 511;
        float4 v = ((const float4*)Wf)[(size_t)o * 512 + c4];
        bf16x4 b; b[0] = (__bf16)v.x; b[1] = (__bf16)v.y; b[2] = (__bf16)v.z; b[3] = (__bf16)v.w;
        *(bf16x4*)&WB[(size_t)o * KX + (c4 << 2)] = b;
    } else if (i < R1 + R2) {
        const int j = i - R1;
        const int o = j >> 6, c = j & 63;
        const int e = c >> 3, r = c & 7;
        WB[(size_t)o * KX + DIN + c] = (__bf16)Bm[((size_t)e * DOUT + o) * RANK + r];
    } else {
        const int j = i - (R1 + R2);
        const int r = j >> 9, c4 = j & 511;
        float4 v;
        if (r < 8)        v = ((const float4*)Wr)[(size_t)r * 512 + c4];
        else if (r < 72)  v = ((const float4*)A)[(size_t)(r - 8) * 512 + c4];
        else              v = make_float4(0.f, 0.f, 0.f, 0.f);
        bf16x4 b; b[0] = (__bf16)v.x; b[1] = (__bf16)v.y; b[2] = (__bf16)v.z; b[3] = (__bf16)v.w;
        *(bf16x4*)&ACAT[(size_t)r * DIN + (c4 << 2)] = b;
    }
}

/* ==== fused h-GEMM: x(fp32)->bf16 convert + XB side-write + MFMA vs ACAT ==== */
__global__ __launch_bounds__(256) void mole_hconv(
    const float* __restrict__ x, const __bf16* __restrict__ ACAT,
    __bf16* __restrict__ XB, float* __restrict__ HP)
{
    __shared__ __align__(16) __bf16 Xs[128][32];
    __shared__ __align__(16) __bf16 Bs[128][32];

    const int tid = threadIdx.x;
    const int wv  = tid >> 6, ln = tid & 63;
    const int wr  = wv >> 1, wc = wv & 1;
    const size_t m0 = (size_t)blockIdx.x * 128;
    const int kStart = blockIdx.z * (DIN / NSPLIT);
    float* C = HP + (size_t)blockIdx.z * BT * HLD;

    const int xr = tid >> 3;
    const int xc = (tid & 7) << 2;
    const float* gx  = x  + (m0 + xr) * (size_t)DIN + kStart + xc;
    __bf16*      gxb = XB + (m0 + xr) * (size_t)KX  + kStart + xc;

    const int srow = (wv << 4) + (ln >> 2);
    const int scol = (ln & 3) << 3;
    const __bf16* gB0 = ACAT + srow * (size_t)DIN + kStart + scol;
    const __bf16* gB1 = gB0 + (size_t)64 * DIN;
    __bf16* lB0 = &Bs[(wv << 4)][0];
    __bf16* lB1 = &Bs[64 + (wv << 4)][0];

    f32x4 acc[4][4] = {};
    const int fr = ln & 15;
    const int fk = (ln >> 4) << 3;

    for (int ks = 0; ks < (DIN / NSPLIT) / 32; ++ks) {
        gload_lds16(gB0, lB0);
        gload_lds16(gB1, lB1);
        gB0 += 32; gB1 += 32;
        #pragma unroll
        for (int j = 0; j < 4; ++j) {
            float4 v = *(const float4*)(gx + (size_t)(32 * j) * DIN + 32 * ks);
            bf16x4 b; b[0] = (__bf16)v.x; b[1] = (__bf16)v.y;
            b[2] = (__bf16)v.z; b[3] = (__bf16)v.w;
            *(bf16x4*)&Xs[xr + 32 * j][xc] = b;
            *(bf16x4*)(gxb + (size_t)(32 * j) * KX + 32 * ks) = b;
        }
        __syncthreads();

        bf16x8 af[4], bfr[4];
        #pragma unroll
        for (int m = 0; m < 4; ++m)
            af[m] = *(const bf16x8*)&Xs[(wr << 6) + (m << 4) + fr][fk];
        #pragma unroll
        for (int n = 0; n < 4; ++n)
            bfr[n] = *(const bf16x8*)&Bs[(wc << 6) + (n << 4) + fr][fk];
        #pragma unroll
        for (int m = 0; m < 4; ++m)
            #pragma unroll
            for (int n = 0; n < 4; ++n)
                acc[m][n] = MFMA16(af[m], bfr[n], acc[m][n]);
        __syncthreads();
    }

    const int cr = (ln >> 4) << 2;
    const int cc = ln & 15;
    #pragma unroll
    for (int n = 0; n < 4; ++n) {
        const int col = (wc << 6) + (n << 4) + cc;
        if (col < HLD) {
            #pragma unroll
            for (int m = 0; m < 4; ++m) {
                const size_t row = m0 + (wr << 6) + (m << 4) + cr;
                #pragma unroll
                for (int r = 0; r < 4; ++r)
                    C[(row + r) * (size_t)HLD + col] = acc[m][n][r];
            }
        }
    }
}

/* --------- per-token: logits (HP cols 0-7 + br) -> softmax -> w; g -> XB --- */
__global__ __launch_bounds__(256) void mole_softmax_g(
    const float* __restrict__ HP, const float* __restrict__ br,
    float* __restrict__ wOut, __bf16* __restrict__ XB)
{
    const int t   = blockIdx.x * 4 + (threadIdx.x >> 6);
    const int tid = threadIdx.x & 63;
    float h = 0.0f;
    #pragma unroll
    for (int sp = 0; sp < NSPLIT; ++sp)
        h += HP[((size_t)sp * BT + t) * HLD + 8 + tid];

    float lg[NEXP];
    #pragma unroll
    for (int e = 0; e < NEXP; ++e) {
        lg[e] = br[e];
        #pragma unroll
        for (int sp = 0; sp < NSPLIT; ++sp)
            lg[e] += HP[((size_t)sp * BT + t) * HLD + e];
    }
    float mx = lg[0];
    #pragma unroll
    for (int e = 1; e < NEXP; ++e) mx = fmaxf(mx, lg[e]);
    float ex[NEXP], den = 0.0f;
    #pragma unroll
    for (int e = 0; e < NEXP; ++e) { ex[e] = expf(lg[e] - mx); den += ex[e]; }

    const float w_my = ex[tid >> 3] / den;
    XB[(size_t)t * KX + DIN + tid] = (__bf16)(SCALING * w_my * h);
    if (tid < NEXP) wOut[(size_t)t * NEXP + tid] = ex[tid] / den;
}

/* ========== main 256x256 GEMM: m201-style 8-phase, BK=64 dbuf ==========
   Best-measured-total configuration (R11: 100.9 / R16: 101.1 us). */
__global__ __launch_bounds__(512, 1) void mole_gemm256(
    const __bf16* __restrict__ XBp, const __bf16* __restrict__ WBp,
    float* __restrict__ C, const float* __restrict__ bias)
{
    __shared__ __align__(16) char smem[131072];

    const int tid = threadIdx.x;
    const int wv  = tid >> 6, l = tid & 63;
    const int wm  = wv >> 2, wn = wv & 3;
    const int bid = blockIdx.x;
    const int xcd = bid & 7, ib = bid >> 3;
    const int tm = xcd * 4 + (ib & 3), tn = ib >> 2;
    const size_t m0 = (size_t)tm * 256, n0 = (size_t)tn * 256;

    const __bf16* gA = XBp + (m0 + (l >> 3)) * KX + (((l & 7) ^ (l >> 3)) << 3);
    const __bf16* gB = WBp + (n0 + (l >> 3)) * KX + (((l & 7) ^ (l >> 3)) << 3);
    const int wv8 = wv * 8;
    const int rbB = ((wv & 3) * 8) + ((wv >> 2) * 64);

    const int fr = l & 15, fq = l >> 4;
    const int sw0 = ((fq)     ^ (fr & 7)) << 4;
    const int sw1 = ((4 + fq) ^ (fr & 7)) << 4;
    const int aOff = (wm * 128 + fr) * 128;
    const int bOff = 32768 + (wn * 64 + fr) * 128;

    f32x4 acc[8][4] = {};
    bf16x8 fa[4][2], fa2[4][2], fb[2][2], fb2[2][2];

#define GLA(RB, T, BUF)                                                       \
    gload_lds16(gA + (size_t)((RB) + wv8) * KX + (size_t)(T) * 64,            \
                smem + (BUF) * 65536 + ((RB) + wv8) * 128)
#define GLB(RB, T, BUF)                                                       \
    gload_lds16(gB + (size_t)((RB) + rbB) * KX + (size_t)(T) * 64,            \
                smem + (BUF) * 65536 + 32768 + ((RB) + rbB) * 128)
#define ST_AQ1(T, BUF) { GLA(0, T, BUF);  GLA(128, T, BUF); }
#define ST_AQ2(T, BUF) { GLA(64, T, BUF); GLA(192, T, BUF); }
#define ST_BH1(T, BUF) { GLB(0, T, BUF);  GLB(128, T, BUF); }
#define ST_BH2(T, BUF) { GLB(32, T, BUF); GLB(160, T, BUF); }

#define RD_FA(ARR, B0, PB)                                                    \
    _Pragma("unroll")                                                         \
    for (int mf = 0; mf < 4; ++mf) {                                          \
        const char* a_ = smem + (PB) * 65536 + aOff + ((B0) + mf) * 2048;     \
        ARR[mf][0] = *(const bf16x8*)(a_ + sw0);                              \
        ARR[mf][1] = *(const bf16x8*)(a_ + sw1);                              \
    }
#define RD_FB(ARR, B0, PB)                                                    \
    _Pragma("unroll")                                                         \
    for (int nf = 0; nf < 2; ++nf) {                                          \
        const char* b_ = smem + (PB) * 65536 + bOff + ((B0) + nf) * 2048;     \
        ARR[nf][0] = *(const bf16x8*)(b_ + sw0);                              \
        ARR[nf][1] = *(const bf16x8*)(b_ + sw1);                              \
    }
#define MM(FA, FB, MB, NB)                                                    \
    __builtin_amdgcn_s_setprio(1);                                            \
    _Pragma("unroll")                                                         \
    for (int kk = 0; kk < 2; ++kk)                                            \
        _Pragma("unroll")                                                     \
        for (int mf = 0; mf < 4; ++mf)                                        \
            _Pragma("unroll")                                                 \
            for (int nf = 0; nf < 2; ++nf)                                    \
                acc[(MB) + mf][(NB) + nf] =                                   \
                    MFMA16(FA[mf][kk], FB[nf][kk], acc[(MB) + mf][(NB) + nf]);\
    __builtin_amdgcn_s_setprio(0);
#define MIDBAR { __builtin_amdgcn_s_barrier();                                \
                 asm volatile("s_waitcnt lgkmcnt(0)" ::: "memory");           \
                 __builtin_amdgcn_sched_barrier(0); }
#define ENDBAR __builtin_amdgcn_s_barrier();
#define LG8    asm volatile("s_waitcnt lgkmcnt(8)" ::: "memory");
#define VMC(N) asm volatile("s_waitcnt vmcnt(" #N ")" ::: "memory");

    ST_AQ1(0, 0); ST_BH1(0, 0); ST_BH2(0, 0); ST_AQ2(0, 0);
    ST_AQ1(1, 1); ST_BH1(1, 1); ST_BH2(1, 1);
    VMC(6); ENDBAR;

    #pragma unroll 1
    for (int i = 0; i < 15; ++i) {
        const int t = 2 * i;
        RD_FA(fa, 0, 0); RD_FB(fb, 0, 0);
        ST_AQ2(t + 1, 1);
        LG8; MIDBAR; MM(fa, fb, 0, 0); ENDBAR;
        RD_FB(fb2, 2, 0);
        ST_AQ1(t + 2, 0);
        MIDBAR; MM(fa, fb2, 0, 2); ENDBAR;
        RD_FA(fa2, 4, 0);
        ST_BH1(t + 2, 0);
        MIDBAR; MM(fa2, fb, 4, 0); ENDBAR;
        ST_BH2(t + 2, 0);
        MIDBAR; MM(fa2, fb2, 4, 2); VMC(6); ENDBAR;
        RD_FA(fa, 0, 1); RD_FB(fb, 0, 1);
        ST_AQ2(t + 2, 0);
        LG8; MIDBAR; MM(fa, fb, 0, 0); ENDBAR;
        RD_FB(fb2, 2, 1);
        ST_AQ1(t + 3, 1);
        MIDBAR; MM(fa, fb2, 0, 2); ENDBAR;
        RD_FA(fa2, 4, 1);
        ST_BH1(t + 3, 1);
        MIDBAR; MM(fa2, fb, 4, 0); ENDBAR;
        ST_BH2(t + 3, 1);
        MIDBAR; MM(fa2, fb2, 4, 2); VMC(6); ENDBAR;
    }
    {
        RD_FA(fa, 0, 0); RD_FB(fb, 0, 0);
        ST_AQ2(31, 1);
        LG8; MIDBAR; MM(fa, fb, 0, 0); ENDBAR;
        RD_FB(fb2, 2, 0);
        ST_AQ1(32, 0);
        MIDBAR; MM(fa, fb2, 0, 2); ENDBAR;
        RD_FA(fa2, 4, 0);
        ST_BH1(32, 0);
        MIDBAR; MM(fa2, fb, 4, 0); ENDBAR;
        ST_BH2(32, 0);
        MIDBAR; MM(fa2, fb2, 4, 2); VMC(6); ENDBAR;
        RD_FA(fa, 0, 1); RD_FB(fb, 0, 1);
        ST_AQ2(32, 0);
        LG8; MIDBAR; MM(fa, fb, 0, 0); ENDBAR;
        RD_FB(fb2, 2, 1);
        MIDBAR; MM(fa, fb2, 0, 2); ENDBAR;
        RD_FA(fa2, 4, 1);
        MIDBAR; MM(fa2, fb, 4, 0); ENDBAR;
        MIDBAR; MM(fa2, fb2, 4, 2); VMC(4); ENDBAR;
    }
    {
        RD_FA(fa, 0, 0); RD_FB(fb, 0, 0);
        LG8; MIDBAR; MM(fa, fb, 0, 0); VMC(2); ENDBAR;
        RD_FB(fb2, 2, 0);
        MIDBAR; MM(fa, fb2, 0, 2); VMC(0); ENDBAR;
        RD_FA(fa2, 4, 0);
        MIDBAR; MM(fa2, fb, 4, 0); ENDBAR;
        MM(fa2, fb2, 4, 2);
    }
#undef GLA
#undef GLB
#undef ST_AQ1
#undef ST_AQ2
#undef ST_BH1
#undef ST_BH2
#undef RD_FA
#undef RD_FB
#undef MM
#undef MIDBAR
#undef ENDBAR
#undef LG8
#undef VMC

    /* epilogue: C = acc + bias */
    const size_t crow = m0 + wm * 128 + fq * 4;
    const size_t ccol = n0 + wn * 64 + fr;
    #pragma unroll
    for (int nf = 0; nf < 4; ++nf) {
        const float bv = bias[ccol + nf * 16];
        #pragma unroll
        for (int mf = 0; mf < 8; ++mf) {
            float* cp = C + (crow + (size_t)mf * 16) * DOUT + ccol + nf * 16;
            #pragma unroll
            for (int i = 0; i < 4; ++i)
                cp[(size_t)i * DOUT] = acc[mf][nf][i] + bv;
        }
    }
}

extern "C" void kernel_launch(void* const* d_in, const int* in_sizes, int n_in,
                              void* d_out, int out_size, void* d_ws, size_t ws_size,
                              hipStream_t stream) {
    const float* x  = (const float*)d_in[0];
    const float* Wf = (const float*)d_in[1];
    const float* bf = (const float*)d_in[2];
    const float* Wr = (const float*)d_in[3];
    const float* br = (const float*)d_in[4];
    const float* A  = (const float*)d_in[5];
    const float* Bm = (const float*)d_in[6];

    float* out0 = (float*)d_out;
    float* wOut = out0 + (size_t)BT * DOUT;

    char* ws = (char*)d_ws;
    __bf16* XB   = (__bf16*)(ws + XB_OFF);
    __bf16* WB   = (__bf16*)(ws + WB_OFF);
    __bf16* ACAT = (__bf16*)(ws + ACAT_OFF);
    float*  HP   = (float*)(ws + HP_OFF);

    /* 1. weights -> bf16 layouts */
    mole_prep<<<4864, 256, 0, stream>>>(Wf, Bm, Wr, A, WB, ACAT);
    /* 2. fused: x->bf16 (+XB side-write) + [logit|h] partials vs ACAT */
    mole_hconv<<<dim3(64, 1, NSPLIT), 256, 0, stream>>>(x, ACAT, XB, HP);
    /* 3. softmax(+br) -> w out; g -> XB tail cols */
    mole_softmax_g<<<BT / 4, 256, 0, stream>>>(HP, br, wOut, XB);
    /* 4. out = [xb|g] @ [Wfb|Bcat]^T + bf  (m201 8-phase) */
    mole_gemm256<<<256, 512, 0, stream>>>(XB, WB, out0, bf);
}